// Round 7
// baseline (1625.480 us; speedup 1.0000x reference)
//
#include <hip/hip_runtime.h>
#include <hip/hip_bf16.h>
#include <math.h>

typedef unsigned short u16;
typedef __attribute__((ext_vector_type(8))) short bfrag;   // 8 bf16 (4 VGPR)
typedef __attribute__((ext_vector_type(4))) float facc;    // 4 fp32 acc
typedef const __attribute__((address_space(1))) void* gaddr_t;
typedef __attribute__((address_space(3))) void* laddr_t;

#define F_RELU   1
#define F_ROWSC  4   // *= rsc[m]
#define F_SIMSC  8   // *= rsc[m]*csc[n]
#define F_RESID2 32  // += bf16 residH + residL

__device__ __forceinline__ u16 f2bf(float f) {
  __hip_bfloat16 h = __float2bfloat16(f);
  return *reinterpret_cast<u16*>(&h);
}
__device__ __forceinline__ float bf2f(u16 u) {
  __hip_bfloat16 h = *reinterpret_cast<__hip_bfloat16*>(&u);
  return __bfloat162float(h);
}
__device__ __forceinline__ float wsum(float v) {
#pragma unroll
  for (int o = 32; o; o >>= 1) v += __shfl_xor(v, o);
  return v;
}
__device__ __forceinline__ float wmaxf(float v) {
#pragma unroll
  for (int o = 32; o; o >>= 1) v = fmaxf(v, __shfl_xor(v, o));
  return v;
}

struct GSeg {
  const u16* A; const u16* B;
  long sA, sB;          // per-z strides
  int lda, ldb, K;      // K % 32 == 0
  int hA, hB;           // per-head offsets (headBits mode)
};

// ---------------------------------------------------------------------------
// bf16 MFMA GEMM, up to 3 K-segments: C = epi(alpha * sum_s A_s @ B_s^T)
// 256 thr = 4 waves; tile 128x128; BK=32; wave = 64x64 (4x4 of 16x16x32).
// DOUBLE-BUFFERED LDS at 2 x 16KB = 32KB total: occupancy stays ~4-5
// blocks/CU (inter-block overlap) AND the glds for iter k+1 issues before
// iter k's barrier, giving each load a full MFMA phase of flight time.
// [R6 post-mortem: dbuf at 64KB was neutral - LDS-capped occupancy ate the
//  pipelining gain; this is the 32KB variant.]
// LDS row stride 32 elems; slot g' = g ^ ((row>>1)&3) -> ds_read_b128 2-way max.
// headBits: blockIdx.z = zb*2 + h; per-head offsets hA/hB/hC.
// ---------------------------------------------------------------------------
__global__ __launch_bounds__(256)
void bgemm_k(GSeg s0, GSeg s1, GSeg s2,
             const float* __restrict__ bias,
             const u16* __restrict__ residH, const u16* __restrict__ residL,
             const float* __restrict__ rsc, const float* __restrict__ csc,
             float* __restrict__ Cf, u16* __restrict__ Cb, u16* __restrict__ Cb2,
             int ldc, long sC, int hC, int headBits, int sS,
             float alpha, int flags, int Mstore)
{
  const int zAll = blockIdx.z;
  const int hIdx = headBits ? (zAll & 1) : 0;
  const int z    = headBits ? (zAll >> 1) : zAll;
  const long cofs = (long)z * sC + (long)hIdx * hC;
  const float* rs = rsc ? rsc + (long)z * sS : nullptr;
  const float* cs = csc ? csc + (long)z * sS : nullptr;

  __shared__ u16 As[2][128 * 32];
  __shared__ u16 Bs[2][128 * 32];

  const int tid  = threadIdx.x;
  const int wave = tid >> 6, lane = tid & 63;
  const int m0 = blockIdx.x * 128, n0 = blockIdx.y * 128;
  const int wrow = (wave >> 1) * 64, wcol = (wave & 1) * 64;

  // per-segment resolved base pointers + iteration split
  const u16* ApS[3]; const u16* BpS[3]; int ldaS[3], ldbS[3];
  ApS[0] = s0.A + (long)z * s0.sA + (long)hIdx * s0.hA;
  BpS[0] = s0.B + (long)z * s0.sB + (long)hIdx * s0.hB;
  ldaS[0] = s0.lda; ldbS[0] = s0.ldb;
  ApS[1] = s1.A ? s1.A + (long)z * s1.sA + (long)hIdx * s1.hA : nullptr;
  BpS[1] = s1.B ? s1.B + (long)z * s1.sB + (long)hIdx * s1.hB : nullptr;
  ldaS[1] = s1.lda; ldbS[1] = s1.ldb;
  ApS[2] = s2.A ? s2.A + (long)z * s2.sA + (long)hIdx * s2.hA : nullptr;
  BpS[2] = s2.B ? s2.B + (long)z * s2.sB + (long)hIdx * s2.hB : nullptr;
  ldaS[2] = s2.lda; ldbS[2] = s2.ldb;
  const int n0i = s0.K >> 5, n1i = n0i + (s1.K >> 5);
  const int nIt = n1i + (s2.K >> 5);

  // staging geometry: wave stages rows [wave*32, wave*32+32) of A and B;
  // one glds inst = 16 rows x 4 groups (64 lanes x 16B = 1KB), two per operand.
  const int lrow = lane >> 2;          // 0..15
  const int lgrp = lane & 3;           // 0..3

  facc acc[4][4];
#pragma unroll
  for (int i = 0; i < 4; ++i)
#pragma unroll
    for (int j = 0; j < 4; ++j) acc[i][j] = (facc)(0.f);

  const int r16 = lane & 15, gq = lane >> 4;

  // stage iteration `it` into buffer `buf`
  auto stage = [&](int buf, int it) {
    int sidx, base;
    if (it < n0i)      { sidx = 0; base = 0; }
    else if (it < n1i) { sidx = 1; base = n0i; }
    else               { sidx = 2; base = n1i; }
    const int k0 = (it - base) << 5;
    const u16* Ab = ApS[sidx];
    const u16* Bb = BpS[sidx];
    const int la = ldaS[sidx], lb = ldbS[sidx];
#pragma unroll
    for (int ss = 0; ss < 2; ++ss) {
      int rloc = wave * 32 + ss * 16;
      int row  = rloc + lrow;
      int g    = lgrp ^ ((row >> 1) & 3);
      __builtin_amdgcn_global_load_lds(
          (gaddr_t)(const void*)(Ab + (long)(m0 + row) * la + k0 + g * 8),
          (laddr_t)(As[buf] + rloc * 32), 16, 0, 0);
      __builtin_amdgcn_global_load_lds(
          (gaddr_t)(const void*)(Bb + (long)(n0 + row) * lb + k0 + g * 8),
          (laddr_t)(Bs[buf] + rloc * 32), 16, 0, 0);
    }
  };

  stage(0, 0);
  for (int it = 0; it < nIt; ++it) {
    const int buf = it & 1;
    __syncthreads();                      // drains glds; buf is ready
    if (it + 1 < nIt) stage(buf ^ 1, it + 1);

    bfrag af[4], bb[4];
#pragma unroll
    for (int mt = 0; mt < 4; ++mt) {
      int r = wrow + mt * 16 + r16;
      int slot = gq ^ ((r >> 1) & 3);
      af[mt] = *(const bfrag*)&As[buf][r * 32 + slot * 8];
    }
#pragma unroll
    for (int nt = 0; nt < 4; ++nt) {
      int r = wcol + nt * 16 + r16;
      int slot = gq ^ ((r >> 1) & 3);
      bb[nt] = *(const bfrag*)&Bs[buf][r * 32 + slot * 8];
    }
#pragma unroll
    for (int mt = 0; mt < 4; ++mt)
#pragma unroll
      for (int nt = 0; nt < 4; ++nt)
        acc[mt][nt] = __builtin_amdgcn_mfma_f32_16x16x32_bf16(
            af[mt], bb[nt], acc[mt][nt], 0, 0, 0);
  }

  // epilogue: C/D layout col = lane&15, row = (lane>>4)*4 + reg
#pragma unroll
  for (int mt = 0; mt < 4; ++mt) {
#pragma unroll
    for (int nt = 0; nt < 4; ++nt) {
#pragma unroll
      for (int r = 0; r < 4; ++r) {
        int gm = m0 + wrow + mt * 16 + gq * 4 + r;
        int gn = n0 + wcol + nt * 16 + r16;
        if (gm >= Mstore) continue;
        float v = acc[mt][nt][r] * alpha;
        long ci = cofs + (long)gm * ldc + gn;
        if (flags & F_SIMSC)  v *= rs[gm] * cs[gn];
        if (flags & F_ROWSC)  v *= rs[gm];
        if (bias)             v += bias[gn];
        if (flags & F_RESID2) v += bf2f(residH[ci]) + bf2f(residL[ci]);
        if (flags & F_RELU)   v = fmaxf(v, 0.f);
        if (Cf) Cf[ci] = v;
        if (Cb) {
          u16 hv = f2bf(v);
          Cb[ci] = hv;
          if (Cb2) Cb2[ci] = f2bf(v - bf2f(hv));
        }
      }
    }
  }
}

// ---------------------------------------------------------------------------
__global__ __launch_bounds__(256)
void castbf_k(const float* __restrict__ in, u16* __restrict__ out, int n)
{
  int i = blockIdx.x * 256 + threadIdx.x;
  if (i < n) out[i] = f2bf(in[i]);
}

// all 7 weight matrices in one launch (layout matches wgt arena)
__global__ __launch_bounds__(256)
void castw_k(const float* w0, const float* w1, const float* w2,
             const float* w3, const float* w4, const float* w5,
             const float* w6, u16* __restrict__ dst)
{
  int i = blockIdx.x * 256 + threadIdx.x;
  const float* s; int off;
  if      (i < 262144)  { s = w0; off = 0; }
  else if (i < 1048576) { s = w1; off = 262144; }
  else if (i < 1310720) { s = w2; off = 1048576; }
  else if (i < 1835008) { s = w3; off = 1310720; }
  else if (i < 2359296) { s = w4; off = 1835008; }
  else if (i < 2883584) { s = w5; off = 2359296; }
  else                  { s = w6; off = 2883584; }
  dst[i] = f2bf(s[i - off]);
}

// x1 = LN(bf16 a + bf16 b) -> hi (in place over a ok) + lo
__global__ __launch_bounds__(256)
void ln1_k(const u16* __restrict__ a, const u16* __restrict__ b,
           const float* __restrict__ g, const float* __restrict__ be,
           u16* __restrict__ oh, u16* __restrict__ ol)
{
  long base = (long)blockIdx.x * 512;
  int t = threadIdx.x;
  float v0 = bf2f(a[base + t])       + bf2f(b[base + t]);
  float v1 = bf2f(a[base + t + 256]) + bf2f(b[base + t + 256]);
  __shared__ float red[4], red2[4];
  float s = wsum(v0 + v1);
  if ((t & 63) == 0) red[t >> 6] = s;
  __syncthreads();
  float mean = (red[0] + red[1] + red[2] + red[3]) * (1.f / 512.f);
  float c0 = v0 - mean, c1 = v1 - mean;
  float ss = wsum(c0 * c0 + c1 * c1);
  if ((t & 63) == 0) red2[t >> 6] = ss;
  __syncthreads();
  float var = (red2[0] + red2[1] + red2[2] + red2[3]) * (1.f / 512.f);
  float rstd = rsqrtf(var + 1e-5f);
  float o0 = c0 * rstd * g[t]       + be[t];
  float o1 = c1 * rstd * g[t + 256] + be[t + 256];
  u16 h0 = f2bf(o0), h1 = f2bf(o1);
  oh[base + t] = h0;       oh[base + t + 256] = h1;
  ol[base + t] = f2bf(o0 - bf2f(h0));
  ol[base + t + 256] = f2bf(o1 - bf2f(h1));
}

// x2 = LN((hi+lo) + bf16 b) -> bf16
__global__ __launch_bounds__(256)
void ln2_k(const u16* __restrict__ hi, const u16* __restrict__ lo,
           const u16* __restrict__ b, const float* __restrict__ g,
           const float* __restrict__ be, u16* __restrict__ ob)
{
  long base = (long)blockIdx.x * 512;
  int t = threadIdx.x;
  float v0 = bf2f(hi[base + t])       + bf2f(lo[base + t])       + bf2f(b[base + t]);
  float v1 = bf2f(hi[base + t + 256]) + bf2f(lo[base + t + 256]) + bf2f(b[base + t + 256]);
  __shared__ float red[4], red2[4];
  float s = wsum(v0 + v1);
  if ((t & 63) == 0) red[t >> 6] = s;
  __syncthreads();
  float mean = (red[0] + red[1] + red[2] + red[3]) * (1.f / 512.f);
  float c0 = v0 - mean, c1 = v1 - mean;
  float ss = wsum(c0 * c0 + c1 * c1);
  if ((t & 63) == 0) red2[t >> 6] = ss;
  __syncthreads();
  float var = (red2[0] + red2[1] + red2[2] + red2[3]) * (1.f / 512.f);
  float rstd = rsqrtf(var + 1e-5f);
  ob[base + t]       = f2bf(c0 * rstd * g[t]       + be[t]);
  ob[base + t + 256] = f2bf(c1 * rstd * g[t + 256] + be[t + 256]);
}

// invn[row] = 1/max(||hi+lo||, 1e-12)
__global__ __launch_bounds__(256)
void rownorm_k(const u16* __restrict__ hi, const u16* __restrict__ lo,
               float* __restrict__ invn)
{
  long base = (long)blockIdx.x * 512;
  int t = threadIdx.x;
  float v0 = bf2f(hi[base + t])       + bf2f(lo[base + t]);
  float v1 = bf2f(hi[base + t + 256]) + bf2f(lo[base + t + 256]);
  __shared__ float red[4];
  float s = wsum(v0 * v0 + v1 * v1);
  if ((t & 63) == 0) red[t >> 6] = s;
  __syncthreads();
  if (t == 0) {
    float tot = red[0] + red[1] + red[2] + red[3];
    invn[blockIdx.x] = 1.f / fmaxf(sqrtf(tot), 1e-12f);
  }
}

// in-place row softmax over 1024 bf16
__global__ __launch_bounds__(256)
void softmaxu_k(u16* __restrict__ sc)
{
  long row = blockIdx.x;
  u16* p = sc + row * 1024;
  int t = threadIdx.x;
  float v[4];
#pragma unroll
  for (int i = 0; i < 4; ++i) v[i] = bf2f(p[t + 256 * i]);
  __shared__ float redm[4], redsum[4];
  float m4 = fmaxf(fmaxf(v[0], v[1]), fmaxf(v[2], v[3]));
  float wm = wmaxf(m4);
  if ((t & 63) == 0) redm[t >> 6] = wm;
  __syncthreads();
  float MX = fmaxf(fmaxf(redm[0], redm[1]), fmaxf(redm[2], redm[3]));
  float s = 0.f;
#pragma unroll
  for (int i = 0; i < 4; ++i) { v[i] = __expf(v[i] - MX); s += v[i]; }
  float ws_ = wsum(s);
  if ((t & 63) == 0) redsum[t >> 6] = ws_;
  __syncthreads();
  float inv = 1.f / (redsum[0] + redsum[1] + redsum[2] + redsum[3]);
#pragma unroll
  for (int i = 0; i < 4; ++i) p[t + 256 * i] = f2bf(v[i] * inv);
}

// 64x64 tiled u16 transpose; z = zb*2+h when headBits
__global__ __launch_bounds__(256)
void transp_k(const u16* __restrict__ in, u16* __restrict__ out,
              int inStride, int outStride, long sIn, long sOut,
              int hIn, int headBits)
{
  const int zAll = blockIdx.z;
  const int h  = headBits ? (zAll & 1) : 0;
  const int zb = headBits ? (zAll >> 1) : zAll;
  const u16* src = in + (long)zb * sIn + (long)h * hIn;
  u16* dst = out + (long)zAll * sOut;
  const int r0 = blockIdx.x * 64, c0 = blockIdx.y * 64;
  __shared__ u16 tile[64][66];
  const int t = threadIdx.x;
#pragma unroll
  for (int p = 0; p < 16; ++p) {
    int idx = p * 256 + t;
    int r = idx >> 6, c = idx & 63;
    tile[r][c] = src[(long)(r0 + r) * inStride + c0 + c];
  }
  __syncthreads();
#pragma unroll
  for (int p = 0; p < 16; ++p) {
    int idx = p * 256 + t;
    int c = idx >> 6, r = idx & 63;
    dst[(long)(c0 + c) * outStride + r0 + r] = tile[r][c];
  }
}

// per-row top-4 (descending, ties -> lower index, matching lax.top_k)
__global__ __launch_bounds__(64)
void topk_k(const float* __restrict__ sim, int* __restrict__ idx4)
{
  long row = blockIdx.x;
  const float* p = sim + row * 1024;
  int t = threadIdx.x;
  int c0 = -1, c1 = -1, c2 = -1, c3 = -1;
#pragma unroll
  for (int pass = 0; pass < 4; ++pass) {
    float best = -INFINITY;
    int bi = 1 << 30;
    for (int j = t; j < 1024; j += 64) {
      if (j == c0 || j == c1 || j == c2 || j == c3) continue;
      float v = p[j];
      if (v > best || (v == best && j < bi)) { best = v; bi = j; }
    }
#pragma unroll
    for (int off = 32; off; off >>= 1) {
      float ov = __shfl_down(best, off);
      int   oi = __shfl_down(bi, off);
      if (ov > best || (ov == best && oi < bi)) { best = ov; bi = oi; }
    }
    bi = __shfl(bi, 0);
    if (pass == 0) c0 = bi; else if (pass == 1) c1 = bi;
    else if (pass == 2) c2 = bi; else c3 = bi;
  }
  if (t == 0) { int* q = idx4 + row * 4; q[0] = c0; q[1] = c1; q[2] = c2; q[3] = c3; }
}

// adjacency -> bf16 + invcnt, from fp32 sim chunk (chunk-local rows)
__global__ __launch_bounds__(256)
void adjbf_k(const float* __restrict__ sim, const int* __restrict__ idx4,
             u16* __restrict__ adjb, float* __restrict__ invcnt)
{
  long row = blockIdx.x;
  int b = (int)(row >> 10);
  int i = (int)(row & 1023);
  const float* prow = sim + row * 1024;
  u16* arow_ = adjb + row * 1024;
  const int* my = idx4 + row * 4;
  int m0 = my[0], m1 = my[1], m2 = my[2], m3 = my[3];
  int t = threadIdx.x;
  float lsum = 0.f;
  for (int j = t; j < 1024; j += 256) {
    float v = prow[j];
    bool present = false;
    if (j != i) {
      present = (j == m0) | (j == m1) | (j == m2) | (j == m3);
      if (!present) {
        const int* oj = idx4 + (((long)b << 10) + j) * 4;
        present = (oj[0] == i) | (oj[1] == i) | (oj[2] == i) | (oj[3] == i);
      }
    }
    float a = present ? v : 0.f;
    arow_[j] = f2bf(a);
    lsum += a;
  }
  __shared__ float red[4];
  float s = wsum(lsum);
  if ((t & 63) == 0) red[t >> 6] = s;
  __syncthreads();
  if (t == 0) {
    float tot = red[0] + red[1] + red[2] + red[3];
    invcnt[row] = 1.f / fmaxf(tot, 1.f);
  }
}

// pooled_bf[128][512]: rows<32 = mean_s x2_bf, rows>=32 = 0
__global__ __launch_bounds__(256)
void poolbf_k(const u16* __restrict__ x2, u16* __restrict__ pooled)
{
  int i = blockIdx.x * 256 + threadIdx.x;   // 0..65535
  int b = i >> 9, d = i & 511;
  float s = 0.f;
  if (b < 32) {
    const u16* p = x2 + ((long)b << 10) * 512 + d;
    for (int sdx = 0; sdx < 1024; ++sdx) s += bf2f(p[(long)sdx * 512]);
    s *= (1.f / 1024.f);
  }
  pooled[i] = f2bf(s);
}

// ---------------------------------------------------------------------------
static inline GSeg mkseg(const u16* A, const u16* B, int K, int lda, int ldb,
                         long sA = 0, long sB = 0, int hA = 0, int hB = 0)
{
  GSeg s; s.A = A; s.B = B; s.K = K; s.lda = lda; s.ldb = ldb;
  s.sA = sA; s.sB = sB; s.hA = hA; s.hB = hB; return s;
}

static inline void bgemm(hipStream_t st, GSeg s0, GSeg s1, GSeg s2,
    const float* bias, const u16* residH, const u16* residL,
    const float* rsc, const float* csc, float* Cf, u16* Cb, u16* Cb2,
    int M, int N, int ldc, long sC, int hC, int headBits, int sS,
    float alpha, int flags, int nz, int Mstore = -1)
{
  dim3 g(M / 128, N / 128, nz);
  bgemm_k<<<g, 256, 0, st>>>(s0, s1, s2, bias, residH, residL,
                             rsc, csc, Cf, Cb, Cb2, ldc, sC, hC, headBits,
                             sS, alpha, flags, Mstore < 0 ? M : Mstore);
}

extern "C" void kernel_launch(void* const* d_in, const int* in_sizes, int n_in,
                              void* d_out, int out_size, void* d_ws, size_t ws_size,
                              hipStream_t stream)
{
  (void)in_sizes; (void)n_in; (void)out_size;
  const float* x     = (const float*)d_in[0];
  const float* enc_w = (const float*)d_in[1];
  const float* enc_b = (const float*)d_in[2];
  const float* in_w  = (const float*)d_in[3];
  const float* in_b  = (const float*)d_in[4];
  const float* out_w = (const float*)d_in[5];
  const float* out_b = (const float*)d_in[6];
  const float* ln1_g = (const float*)d_in[7];
  const float* ln1_b = (const float*)d_in[8];
  const float* fw1   = (const float*)d_in[9];
  const float* fb1   = (const float*)d_in[10];
  const float* fw2   = (const float*)d_in[11];
  const float* fb2   = (const float*)d_in[12];
  const float* gc_w  = (const float*)d_in[13];
  const float* gc_b  = (const float*)d_in[14];
  const float* ln2_g = (const float*)d_in[15];
  const float* ln2_b = (const float*)d_in[16];
  const float* dec_w = (const float*)d_in[17];
  const float* dec_b = (const float*)d_in[18];
  float* out = (float*)d_out;

  // ---- arena ----
  char* base = (char*)d_ws;
  u16*  bf1  = (u16*)(base);                  // h_bf -> x1_hi (in place)
  u16*  lob  = (u16*)(base + 33554432);       // x1_lo
  u16*  bf2  = (u16*)(base + 67108864);       // ctx -> nsum -> x2
  u16*  wgt  = (u16*)(base + 100663296);      // bf16 weights
  float* invn    = (float*)(base + 106954752);
  float* invcnt  = (float*)(base + 107085824);
  u16*   pooledb = (u16*)(base + 107216896);
  int*   idx4    = (int*)(base + 107347968);
  char*  scr     = base + 107872256;          // 80MB scratch, phase-multiplexed
  const size_t need = 107872256 + 83886080;
  if (ws_size < need) return;

  u16* encw = wgt;
  u16* inw  = wgt + 262144;
  u16* outw = wgt + 1048576;
  u16* fw1b = wgt + 1310720;
  u16* fw2b = wgt + 1835008;
  u16* gcwb = wgt + 2359296;
  u16* decw = wgt + 2883584;

  const int Mtok = 32768;
  GSeg Z = mkseg(nullptr, nullptr, 0, 0, 0);

  // ---- casts ----
  u16* xbf = (u16*)scr;
  castbf_k<<<65536, 256, 0, stream>>>(x, xbf, 16777216);
  castw_k<<<12288, 256, 0, stream>>>(enc_w, in_w, out_w, fw1, fw2, gc_w, dec_w, wgt);

  // 1. h_bf = relu(x @ enc_w^T + enc_b)
  bgemm(stream, mkseg(xbf, encw, 512, 512, 512), Z, Z,
        enc_b, nullptr, nullptr, nullptr, nullptr, nullptr, bf1, nullptr,
        Mtok, 512, 512, 0, 0, 0, 0, 1.f, F_RELU, 1);

  // 2+3. attention: 4 chunks x 8 batches, heads folded into z (z=16)
  for (int c = 0; c < 4; ++c) {
    long row0 = (long)c * 8192;
    u16* qkvc = (u16*)scr;                        // 8192x1536 u16 (24MB)
    u16* sco  = (u16*)(scr + 25165824);           // 16 x 1024x1024 u16 (32MB)
    u16* vT   = (u16*)(scr + 58720256);           // 16 x 256x1024 u16 (8MB)
    bgemm(stream, mkseg(bf1 + row0 * 512, inw, 512, 512, 512), Z, Z,
          in_b, nullptr, nullptr, nullptr, nullptr, nullptr, qkvc, nullptr,
          8192, 1536, 1536, 0, 0, 0, 0, 1.f, 0, 1);
    // scores[z=16] = 1/16 * Q @ K^T  -> bf16
    bgemm(stream, mkseg(qkvc, qkvc + 512, 256, 1536, 1536,
                        1572864, 1572864, 256, 256), Z, Z,
          nullptr, nullptr, nullptr, nullptr, nullptr, nullptr, sco, nullptr,
          1024, 1024, 1024, 2097152, 1048576, 1, 0, 0.0625f, 0, 16);
    softmaxu_k<<<16384, 256, 0, stream>>>(sco);
    transp_k<<<dim3(16, 4, 16), 256, 0, stream>>>(
        qkvc + 1024, vT, 1536, 1024, 1572864, 262144, 256, 1);
    // ctx = P @ V  (B = V^T rows = d, cols = s)
    bgemm(stream, mkseg(sco, vT, 1024, 1024, 1024,
                        2097152, 524288, 1048576, 262144), Z, Z,
          nullptr, nullptr, nullptr, nullptr, nullptr, nullptr,
          bf2 + row0 * 512, nullptr,
          1024, 256, 512, 524288, 256, 1, 0, 1.f, 0, 16);
  }

  // 4. attn_out -> bf16
  u16* aoc = (u16*)scr;                           // 32MB
  bgemm(stream, mkseg(bf2, outw, 512, 512, 512), Z, Z,
        out_b, nullptr, nullptr, nullptr, nullptr, nullptr, aoc, nullptr,
        Mtok, 512, 512, 0, 0, 0, 0, 1.f, 0, 1);

  // 5. x1 = LN(h + attn_out) -> hi (in place) + lo
  ln1_k<<<Mtok, 256, 0, stream>>>(bf1, aoc, ln1_g, ln1_b, bf1, lob);

  // 6+7. FFN
  u16* mid = (u16*)scr;                           // 64MB
  bgemm(stream, mkseg(bf1, fw1b, 512, 512, 512), Z, Z,
        fb1, nullptr, nullptr, nullptr, nullptr, nullptr, mid, nullptr,
        Mtok, 1024, 1024, 0, 0, 0, 0, 1.f, F_RELU, 1);
  bgemm(stream, mkseg(mid, fw2b, 1024, 1024, 1024), Z, Z,
        fb2, bf1, lob, nullptr, nullptr, nullptr, bf1, lob,
        Mtok, 512, 512, 0, 0, 0, 0, 1.f, F_RESID2, 1);

  // 8. row norms
  rownorm_k<<<Mtok, 256, 0, stream>>>(bf1, lob, invn);

  // 9-12. graph: x1T once, then 4 chunks x 8 batches
  float* simc = (float*)scr;                      // 32MB
  u16*   adjb = (u16*)(scr + 33554432);           // 16MB
  u16*   x1T  = (u16*)(scr + 50331648);           // 32MB (all 32 batches)
  transp_k<<<dim3(16, 8, 32), 256, 0, stream>>>(bf1, x1T, 512, 1024,
                                                524288, 524288, 0, 0);
  for (int g = 0; g < 4; ++g) {
    long row0 = (long)g * 8192;
    // sim = (hi.hi^T) * invn_i * invn_j  (bf16 inputs, fp32 acc)
    bgemm(stream,
          mkseg(bf1 + row0 * 512, bf1 + row0 * 512, 512, 512, 512, 524288, 524288),
          Z, Z, nullptr, nullptr, nullptr, invn + row0, invn + row0,
          simc, nullptr, nullptr,
          1024, 1024, 1024, 1048576, 0, 0, 1024, 1.f, F_SIMSC, 8);
    topk_k<<<8192, 64, 0, stream>>>(simc, idx4 + row0 * 4);
    adjbf_k<<<8192, 256, 0, stream>>>(simc, idx4 + row0 * 4, adjb, invcnt + row0);
    // nsum = (adj @ x1) * invcnt
    bgemm(stream, mkseg(adjb, x1T + row0 * 512, 1024, 1024, 1024,
                        1048576, 524288), Z, Z,
          nullptr, nullptr, nullptr, invcnt + row0, nullptr, nullptr,
          bf2 + row0 * 512, nullptr,
          1024, 512, 512, 524288, 0, 0, 1024, 1.f, F_ROWSC, 8);
  }

  // 13/14. gcout = x1_hi @ gcW1^T + nsum @ gcW2^T + gc_b  (2-seg) -> bf16
  u16* gch = (u16*)scr;                           // 32MB
  bgemm(stream, mkseg(bf1, gcwb, 512, 512, 1024),
        mkseg(bf2, gcwb + 512, 512, 512, 1024), Z,
        gc_b, nullptr, nullptr, nullptr, nullptr, nullptr, gch, nullptr,
        Mtok, 512, 512, 0, 0, 0, 0, 1.f, 0, 1);

  // 15. x2 = LN(x1 + gcout) -> bf16 (over bf2; nsum consumed)
  ln2_k<<<Mtok, 256, 0, stream>>>(bf1, lob, gch, ln2_g, ln2_b, bf2);

  // 16+17. pool + decoder
  poolbf_k<<<256, 256, 0, stream>>>(bf2, pooledb);
  bgemm(stream, mkseg(pooledb, decw, 512, 512, 512), Z, Z,
        dec_b, nullptr, nullptr, nullptr, nullptr, out, nullptr, nullptr,
        128, 512, 512, 0, 0, 0, 0, 1.f, 0, 1, 32);
}

// Round 8
// 1533.972 us; speedup vs baseline: 1.0597x; 1.0597x over previous
//
#include <hip/hip_runtime.h>
#include <hip/hip_bf16.h>
#include <math.h>

typedef unsigned short u16;
typedef __attribute__((ext_vector_type(8))) short bfrag;   // 8 bf16 (4 VGPR)
typedef __attribute__((ext_vector_type(4))) float facc;    // 4 fp32 acc
typedef const __attribute__((address_space(1))) void* gaddr_t;
typedef __attribute__((address_space(3))) void* laddr_t;

#define F_RELU   1
#define F_ROWSC  4   // *= rsc[m]
#define F_SIMSC  8   // *= rsc[m]*csc[n]
#define F_RESID2 32  // += bf16 residH + residL

__device__ __forceinline__ u16 f2bf(float f) {
  __hip_bfloat16 h = __float2bfloat16(f);
  return *reinterpret_cast<u16*>(&h);
}
__device__ __forceinline__ float bf2f(u16 u) {
  __hip_bfloat16 h = *reinterpret_cast<__hip_bfloat16*>(&u);
  return __bfloat162float(h);
}
__device__ __forceinline__ float wsum(float v) {
#pragma unroll
  for (int o = 32; o; o >>= 1) v += __shfl_xor(v, o);
  return v;
}
__device__ __forceinline__ float wmaxf(float v) {
#pragma unroll
  for (int o = 32; o; o >>= 1) v = fmaxf(v, __shfl_xor(v, o));
  return v;
}

struct GSeg {
  const u16* A; const u16* B;
  long sA, sB;          // per-z strides
  int lda, ldb, K;      // K % 64 == 0
  int hA, hB;           // per-head offsets (headBits mode)
};

// ---------------------------------------------------------------------------
// bf16 MFMA GEMM, up to 3 K-segments (R6 engine — best measured variant):
// 256 thr = 4 waves; tile 128x128; BK=64; wave = 64x64 (4x4 of 16x16x32).
// Double-buffered LDS 2x32KB. [R7 post-mortem: BK=32 dbuf regressed (137us
// vs 111us top dispatch); BK=64 single also slower. Do not touch.]
// ---------------------------------------------------------------------------
__global__ __launch_bounds__(256)
void bgemm_k(GSeg s0, GSeg s1, GSeg s2,
             const float* __restrict__ bias,
             const u16* __restrict__ residH, const u16* __restrict__ residL,
             const float* __restrict__ rsc, const float* __restrict__ csc,
             float* __restrict__ Cf, u16* __restrict__ Cb, u16* __restrict__ Cb2,
             int ldc, long sC, int hC, int headBits, int sS,
             float alpha, int flags, int Mstore)
{
  const int zAll = blockIdx.z;
  const int hIdx = headBits ? (zAll & 1) : 0;
  const int z    = headBits ? (zAll >> 1) : zAll;
  const long cofs = (long)z * sC + (long)hIdx * hC;
  const float* rs = rsc ? rsc + (long)z * sS : nullptr;
  const float* cs = csc ? csc + (long)z * sS : nullptr;

  __shared__ u16 As[2][128 * 64];
  __shared__ u16 Bs[2][128 * 64];

  const int tid  = threadIdx.x;
  const int wave = tid >> 6, lane = tid & 63;
  const int m0 = blockIdx.x * 128, n0 = blockIdx.y * 128;
  const int wrow = (wave >> 1) * 64, wcol = (wave & 1) * 64;

  const u16* ApS[3]; const u16* BpS[3]; int ldaS[3], ldbS[3];
  ApS[0] = s0.A + (long)z * s0.sA + (long)hIdx * s0.hA;
  BpS[0] = s0.B + (long)z * s0.sB + (long)hIdx * s0.hB;
  ldaS[0] = s0.lda; ldbS[0] = s0.ldb;
  ApS[1] = s1.A ? s1.A + (long)z * s1.sA + (long)hIdx * s1.hA : nullptr;
  BpS[1] = s1.B ? s1.B + (long)z * s1.sB + (long)hIdx * s1.hB : nullptr;
  ldaS[1] = s1.lda; ldbS[1] = s1.ldb;
  ApS[2] = s2.A ? s2.A + (long)z * s2.sA + (long)hIdx * s2.hA : nullptr;
  BpS[2] = s2.B ? s2.B + (long)z * s2.sB + (long)hIdx * s2.hB : nullptr;
  ldaS[2] = s2.lda; ldbS[2] = s2.ldb;
  const int n0i = s0.K >> 6, n1i = n0i + (s1.K >> 6);
  const int nIt = n1i + (s2.K >> 6);

  const int lrow = lane >> 3;          // 0..7
  const int lgrp = lane & 7;           // 0..7

  facc acc[4][4];
#pragma unroll
  for (int i = 0; i < 4; ++i)
#pragma unroll
    for (int j = 0; j < 4; ++j) acc[i][j] = (facc)(0.f);

  const int r16 = lane & 15, gq = lane >> 4;

  auto stage = [&](int buf, int it) {
    int sidx, base;
    if (it < n0i)      { sidx = 0; base = 0; }
    else if (it < n1i) { sidx = 1; base = n0i; }
    else               { sidx = 2; base = n1i; }
    const int k0 = (it - base) << 6;
    const u16* Ab = ApS[sidx];
    const u16* Bb = BpS[sidx];
    const int la = ldaS[sidx], lb = ldbS[sidx];
#pragma unroll
    for (int ss = 0; ss < 4; ++ss) {
      int rloc = wave * 32 + ss * 8;
      int row  = rloc + lrow;
      int g    = lgrp ^ ((row >> 1) & 7);
      __builtin_amdgcn_global_load_lds(
          (gaddr_t)(const void*)(Ab + (long)(m0 + row) * la + k0 + g * 8),
          (laddr_t)(As[buf] + rloc * 64), 16, 0, 0);
      __builtin_amdgcn_global_load_lds(
          (gaddr_t)(const void*)(Bb + (long)(n0 + row) * lb + k0 + g * 8),
          (laddr_t)(Bs[buf] + rloc * 64), 16, 0, 0);
    }
  };

  stage(0, 0);
  for (int it = 0; it < nIt; ++it) {
    const int buf = it & 1;
    __syncthreads();                      // drains glds; buf ready
    if (it + 1 < nIt) stage(buf ^ 1, it + 1);

#pragma unroll
    for (int kk = 0; kk < 2; ++kk) {
      bfrag af[4], bb[4];
#pragma unroll
      for (int mt = 0; mt < 4; ++mt) {
        int r = wrow + mt * 16 + r16;
        int slot = (kk * 4 + gq) ^ ((r >> 1) & 7);
        af[mt] = *(const bfrag*)&As[buf][r * 64 + slot * 8];
      }
#pragma unroll
      for (int nt = 0; nt < 4; ++nt) {
        int r = wcol + nt * 16 + r16;
        int slot = (kk * 4 + gq) ^ ((r >> 1) & 7);
        bb[nt] = *(const bfrag*)&Bs[buf][r * 64 + slot * 8];
      }
#pragma unroll
      for (int mt = 0; mt < 4; ++mt)
#pragma unroll
        for (int nt = 0; nt < 4; ++nt)
          acc[mt][nt] = __builtin_amdgcn_mfma_f32_16x16x32_bf16(
              af[mt], bb[nt], acc[mt][nt], 0, 0, 0);
    }
  }

  // epilogue: C/D layout col = lane&15, row = (lane>>4)*4 + reg
#pragma unroll
  for (int mt = 0; mt < 4; ++mt) {
#pragma unroll
    for (int nt = 0; nt < 4; ++nt) {
#pragma unroll
      for (int r = 0; r < 4; ++r) {
        int gm = m0 + wrow + mt * 16 + gq * 4 + r;
        int gn = n0 + wcol + nt * 16 + r16;
        if (gm >= Mstore) continue;
        float v = acc[mt][nt][r] * alpha;
        long ci = cofs + (long)gm * ldc + gn;
        if (flags & F_SIMSC)  v *= rs[gm] * cs[gn];
        if (flags & F_ROWSC)  v *= rs[gm];
        if (bias)             v += bias[gn];
        if (flags & F_RESID2) v += bf2f(residH[ci]) + bf2f(residL[ci]);
        if (flags & F_RELU)   v = fmaxf(v, 0.f);
        if (Cf) Cf[ci] = v;
        if (Cb) {
          u16 hv = f2bf(v);
          Cb[ci] = hv;
          if (Cb2) Cb2[ci] = f2bf(v - bf2f(hv));
        }
      }
    }
  }
}

// ---------------------------------------------------------------------------
__global__ __launch_bounds__(256)
void castbf_k(const float* __restrict__ in, u16* __restrict__ out, int n)
{
  int i = blockIdx.x * 256 + threadIdx.x;
  if (i < n) out[i] = f2bf(in[i]);
}

// all 7 weight matrices in one launch (layout matches wgt arena)
__global__ __launch_bounds__(256)
void castw_k(const float* w0, const float* w1, const float* w2,
             const float* w3, const float* w4, const float* w5,
             const float* w6, u16* __restrict__ dst)
{
  int i = blockIdx.x * 256 + threadIdx.x;
  const float* s; int off;
  if      (i < 262144)  { s = w0; off = 0; }
  else if (i < 1048576) { s = w1; off = 262144; }
  else if (i < 1310720) { s = w2; off = 1048576; }
  else if (i < 1835008) { s = w3; off = 1310720; }
  else if (i < 2359296) { s = w4; off = 1835008; }
  else if (i < 2883584) { s = w5; off = 2359296; }
  else                  { s = w6; off = 2883584; }
  dst[i] = f2bf(s[i - off]);
}

// x1 = LN(bf16 a + bf16 b) -> hi (in place over a ok) + lo
__global__ __launch_bounds__(256)
void ln1_k(const u16* __restrict__ a, const u16* __restrict__ b,
           const float* __restrict__ g, const float* __restrict__ be,
           u16* __restrict__ oh, u16* __restrict__ ol)
{
  long base = (long)blockIdx.x * 512;
  int t = threadIdx.x;
  float v0 = bf2f(a[base + t])       + bf2f(b[base + t]);
  float v1 = bf2f(a[base + t + 256]) + bf2f(b[base + t + 256]);
  __shared__ float red[4], red2[4];
  float s = wsum(v0 + v1);
  if ((t & 63) == 0) red[t >> 6] = s;
  __syncthreads();
  float mean = (red[0] + red[1] + red[2] + red[3]) * (1.f / 512.f);
  float c0 = v0 - mean, c1 = v1 - mean;
  float ss = wsum(c0 * c0 + c1 * c1);
  if ((t & 63) == 0) red2[t >> 6] = ss;
  __syncthreads();
  float var = (red2[0] + red2[1] + red2[2] + red2[3]) * (1.f / 512.f);
  float rstd = rsqrtf(var + 1e-5f);
  float o0 = c0 * rstd * g[t]       + be[t];
  float o1 = c1 * rstd * g[t + 256] + be[t + 256];
  u16 h0 = f2bf(o0), h1 = f2bf(o1);
  oh[base + t] = h0;       oh[base + t + 256] = h1;
  ol[base + t] = f2bf(o0 - bf2f(h0));
  ol[base + t + 256] = f2bf(o1 - bf2f(h1));
}

// x2 = LN((hi+lo) + bf16 b) -> bf16
__global__ __launch_bounds__(256)
void ln2_k(const u16* __restrict__ hi, const u16* __restrict__ lo,
           const u16* __restrict__ b, const float* __restrict__ g,
           const float* __restrict__ be, u16* __restrict__ ob)
{
  long base = (long)blockIdx.x * 512;
  int t = threadIdx.x;
  float v0 = bf2f(hi[base + t])       + bf2f(lo[base + t])       + bf2f(b[base + t]);
  float v1 = bf2f(hi[base + t + 256]) + bf2f(lo[base + t + 256]) + bf2f(b[base + t + 256]);
  __shared__ float red[4], red2[4];
  float s = wsum(v0 + v1);
  if ((t & 63) == 0) red[t >> 6] = s;
  __syncthreads();
  float mean = (red[0] + red[1] + red[2] + red[3]) * (1.f / 512.f);
  float c0 = v0 - mean, c1 = v1 - mean;
  float ss = wsum(c0 * c0 + c1 * c1);
  if ((t & 63) == 0) red2[t >> 6] = ss;
  __syncthreads();
  float var = (red2[0] + red2[1] + red2[2] + red2[3]) * (1.f / 512.f);
  float rstd = rsqrtf(var + 1e-5f);
  ob[base + t]       = f2bf(c0 * rstd * g[t]       + be[t]);
  ob[base + t + 256] = f2bf(c1 * rstd * g[t + 256] + be[t + 256]);
}

// invn[row] = 1/max(||hi+lo||, 1e-12)
__global__ __launch_bounds__(256)
void rownorm_k(const u16* __restrict__ hi, const u16* __restrict__ lo,
               float* __restrict__ invn)
{
  long base = (long)blockIdx.x * 512;
  int t = threadIdx.x;
  float v0 = bf2f(hi[base + t])       + bf2f(lo[base + t]);
  float v1 = bf2f(hi[base + t + 256]) + bf2f(lo[base + t + 256]);
  __shared__ float red[4];
  float s = wsum(v0 * v0 + v1 * v1);
  if ((t & 63) == 0) red[t >> 6] = s;
  __syncthreads();
  if (t == 0) {
    float tot = red[0] + red[1] + red[2] + red[3];
    invn[blockIdx.x] = 1.f / fmaxf(sqrtf(tot), 1e-12f);
  }
}

// in-place row softmax over 1024 bf16
__global__ __launch_bounds__(256)
void softmaxu_k(u16* __restrict__ sc)
{
  long row = blockIdx.x;
  u16* p = sc + row * 1024;
  int t = threadIdx.x;
  float v[4];
#pragma unroll
  for (int i = 0; i < 4; ++i) v[i] = bf2f(p[t + 256 * i]);
  __shared__ float redm[4], redsum[4];
  float m4 = fmaxf(fmaxf(v[0], v[1]), fmaxf(v[2], v[3]));
  float wm = wmaxf(m4);
  if ((t & 63) == 0) redm[t >> 6] = wm;
  __syncthreads();
  float MX = fmaxf(fmaxf(redm[0], redm[1]), fmaxf(redm[2], redm[3]));
  float s = 0.f;
#pragma unroll
  for (int i = 0; i < 4; ++i) { v[i] = __expf(v[i] - MX); s += v[i]; }
  float ws_ = wsum(s);
  if ((t & 63) == 0) redsum[t >> 6] = ws_;
  __syncthreads();
  float inv = 1.f / (redsum[0] + redsum[1] + redsum[2] + redsum[3]);
#pragma unroll
  for (int i = 0; i < 4; ++i) p[t + 256 * i] = f2bf(v[i] * inv);
}

// 64x64 tiled u16 transpose; z = zb*2+h when headBits
__global__ __launch_bounds__(256)
void transp_k(const u16* __restrict__ in, u16* __restrict__ out,
              int inStride, int outStride, long sIn, long sOut,
              int hIn, int headBits)
{
  const int zAll = blockIdx.z;
  const int h  = headBits ? (zAll & 1) : 0;
  const int zb = headBits ? (zAll >> 1) : zAll;
  const u16* src = in + (long)zb * sIn + (long)h * hIn;
  u16* dst = out + (long)zAll * sOut;
  const int r0 = blockIdx.x * 64, c0 = blockIdx.y * 64;
  __shared__ u16 tile[64][66];
  const int t = threadIdx.x;
#pragma unroll
  for (int p = 0; p < 16; ++p) {
    int idx = p * 256 + t;
    int r = idx >> 6, c = idx & 63;
    tile[r][c] = src[(long)(r0 + r) * inStride + c0 + c];
  }
  __syncthreads();
#pragma unroll
  for (int p = 0; p < 16; ++p) {
    int idx = p * 256 + t;
    int c = idx >> 6, r = idx & 63;
    dst[(long)(c0 + c) * outStride + r0 + r] = tile[r][c];
  }
}

// per-row top-4 from bf16 sim, row cached in LDS (one HBM read per row).
// descending, ties -> lower index (matches lax.top_k).
__global__ __launch_bounds__(256)
void topk_k(const u16* __restrict__ sim, int* __restrict__ idx4)
{
  __shared__ float row[1024];
  __shared__ float bv[4];
  __shared__ int   bidx[4];
  long r = blockIdx.x;
  const u16* p = sim + r * 1024;
  int t = threadIdx.x;
  for (int i = t; i < 1024; i += 256) row[i] = bf2f(p[i]);
  __syncthreads();
  int c0 = -1, c1 = -1, c2 = -1, c3 = -1;
#pragma unroll
  for (int pass = 0; pass < 4; ++pass) {
    float best = -INFINITY;
    int bi = 1 << 30;
#pragma unroll
    for (int q = 0; q < 4; ++q) {
      int j = t + q * 256;
      if (j == c0 || j == c1 || j == c2 || j == c3) continue;
      float v = row[j];
      if (v > best || (v == best && j < bi)) { best = v; bi = j; }
    }
#pragma unroll
    for (int off = 32; off; off >>= 1) {
      float ov = __shfl_down(best, off);
      int   oi = __shfl_down(bi, off);
      if (ov > best || (ov == best && oi < bi)) { best = ov; bi = oi; }
    }
    if ((t & 63) == 0) { bv[t >> 6] = best; bidx[t >> 6] = bi; }
    __syncthreads();
    if (t == 0) {
      float bb = bv[0]; int ii = bidx[0];
#pragma unroll
      for (int w = 1; w < 4; ++w)
        if (bv[w] > bb || (bv[w] == bb && bidx[w] < ii)) { bb = bv[w]; ii = bidx[w]; }
      bidx[0] = ii;
    }
    __syncthreads();
    int sel = bidx[0];
    if (pass == 0) c0 = sel; else if (pass == 1) c1 = sel;
    else if (pass == 2) c2 = sel; else c3 = sel;
    __syncthreads();
  }
  if (t == 0) { int* q = idx4 + r * 4; q[0] = c0; q[1] = c1; q[2] = c2; q[3] = c3; }
}

// adjacency IN PLACE over bf16 sim + invcnt (chunk-local rows)
__global__ __launch_bounds__(256)
void adjbf_k(u16* __restrict__ simadj, const int* __restrict__ idx4,
             float* __restrict__ invcnt)
{
  long row = blockIdx.x;
  int b = (int)(row >> 10);
  int i = (int)(row & 1023);
  u16* prow = simadj + row * 1024;
  const int* my = idx4 + row * 4;
  int m0 = my[0], m1 = my[1], m2 = my[2], m3 = my[3];
  int t = threadIdx.x;
  float lsum = 0.f;
  for (int j = t; j < 1024; j += 256) {
    float v = bf2f(prow[j]);
    bool present = false;
    if (j != i) {
      present = (j == m0) | (j == m1) | (j == m2) | (j == m3);
      if (!present) {
        const int* oj = idx4 + (((long)b << 10) + j) * 4;
        present = (oj[0] == i) | (oj[1] == i) | (oj[2] == i) | (oj[3] == i);
      }
    }
    float a = present ? v : 0.f;
    prow[j] = present ? prow[j] : (u16)0;   // bf16 0.0 == 0x0000
    lsum += a;
  }
  __shared__ float red[4];
  float s = wsum(lsum);
  if ((t & 63) == 0) red[t >> 6] = s;
  __syncthreads();
  if (t == 0) {
    float tot = red[0] + red[1] + red[2] + red[3];
    invcnt[row] = 1.f / fmaxf(tot, 1.f);
  }
}

// pooled_bf[128][512]: rows<32 = mean_s x2_bf, rows>=32 = 0
__global__ __launch_bounds__(256)
void poolbf_k(const u16* __restrict__ x2, u16* __restrict__ pooled)
{
  int i = blockIdx.x * 256 + threadIdx.x;   // 0..65535
  int b = i >> 9, d = i & 511;
  float s = 0.f;
  if (b < 32) {
    const u16* p = x2 + ((long)b << 10) * 512 + d;
    for (int sdx = 0; sdx < 1024; ++sdx) s += bf2f(p[(long)sdx * 512]);
    s *= (1.f / 1024.f);
  }
  pooled[i] = f2bf(s);
}

// ---------------------------------------------------------------------------
static inline GSeg mkseg(const u16* A, const u16* B, int K, int lda, int ldb,
                         long sA = 0, long sB = 0, int hA = 0, int hB = 0)
{
  GSeg s; s.A = A; s.B = B; s.K = K; s.lda = lda; s.ldb = ldb;
  s.sA = sA; s.sB = sB; s.hA = hA; s.hB = hB; return s;
}

static inline void bgemm(hipStream_t st, GSeg s0, GSeg s1, GSeg s2,
    const float* bias, const u16* residH, const u16* residL,
    const float* rsc, const float* csc, float* Cf, u16* Cb, u16* Cb2,
    int M, int N, int ldc, long sC, int hC, int headBits, int sS,
    float alpha, int flags, int nz, int Mstore = -1)
{
  dim3 g(M / 128, N / 128, nz);
  bgemm_k<<<g, 256, 0, st>>>(s0, s1, s2, bias, residH, residL,
                             rsc, csc, Cf, Cb, Cb2, ldc, sC, hC, headBits,
                             sS, alpha, flags, Mstore < 0 ? M : Mstore);
}

extern "C" void kernel_launch(void* const* d_in, const int* in_sizes, int n_in,
                              void* d_out, int out_size, void* d_ws, size_t ws_size,
                              hipStream_t stream)
{
  (void)in_sizes; (void)n_in; (void)out_size;
  const float* x     = (const float*)d_in[0];
  const float* enc_w = (const float*)d_in[1];
  const float* enc_b = (const float*)d_in[2];
  const float* in_w  = (const float*)d_in[3];
  const float* in_b  = (const float*)d_in[4];
  const float* out_w = (const float*)d_in[5];
  const float* out_b = (const float*)d_in[6];
  const float* ln1_g = (const float*)d_in[7];
  const float* ln1_b = (const float*)d_in[8];
  const float* fw1   = (const float*)d_in[9];
  const float* fb1   = (const float*)d_in[10];
  const float* fw2   = (const float*)d_in[11];
  const float* fb2   = (const float*)d_in[12];
  const float* gc_w  = (const float*)d_in[13];
  const float* gc_b  = (const float*)d_in[14];
  const float* ln2_g = (const float*)d_in[15];
  const float* ln2_b = (const float*)d_in[16];
  const float* dec_w = (const float*)d_in[17];
  const float* dec_b = (const float*)d_in[18];
  float* out = (float*)d_out;

  // ---- arena ----
  char* base = (char*)d_ws;
  u16*  bf1  = (u16*)(base);                  // h_bf -> x1_hi (in place)
  u16*  lob  = (u16*)(base + 33554432);       // x1_lo
  u16*  bf2  = (u16*)(base + 67108864);       // ctx -> nsum -> x2
  u16*  wgt  = (u16*)(base + 100663296);      // bf16 weights
  float* invn    = (float*)(base + 106954752);
  float* invcnt  = (float*)(base + 107085824);
  u16*   pooledb = (u16*)(base + 107216896);
  int*   idx4    = (int*)(base + 107347968);
  char*  scr     = base + 107872256;          // 80MB scratch, phase-multiplexed
  const size_t need = 107872256 + 83886080;
  if (ws_size < need) return;

  u16* encw = wgt;
  u16* inw  = wgt + 262144;
  u16* outw = wgt + 1048576;
  u16* fw1b = wgt + 1310720;
  u16* fw2b = wgt + 1835008;
  u16* gcwb = wgt + 2359296;
  u16* decw = wgt + 2883584;

  const int Mtok = 32768;
  GSeg Z = mkseg(nullptr, nullptr, 0, 0, 0);

  // ---- casts ----
  u16* xbf = (u16*)scr;
  castbf_k<<<65536, 256, 0, stream>>>(x, xbf, 16777216);
  castw_k<<<12288, 256, 0, stream>>>(enc_w, in_w, out_w, fw1, fw2, gc_w, dec_w, wgt);

  // 1. h_bf = relu(x @ enc_w^T + enc_b)
  bgemm(stream, mkseg(xbf, encw, 512, 512, 512), Z, Z,
        enc_b, nullptr, nullptr, nullptr, nullptr, nullptr, bf1, nullptr,
        Mtok, 512, 512, 0, 0, 0, 0, 1.f, F_RELU, 1);

  // 2+3. attention: 4 chunks x 8 batches, heads folded into z (z=16)
  for (int c = 0; c < 4; ++c) {
    long row0 = (long)c * 8192;
    u16* qkvc = (u16*)scr;                        // 8192x1536 u16 (24MB)
    u16* sco  = (u16*)(scr + 25165824);           // 16 x 1024x1024 u16 (32MB)
    u16* vT   = (u16*)(scr + 58720256);           // 16 x 256x1024 u16 (8MB)
    bgemm(stream, mkseg(bf1 + row0 * 512, inw, 512, 512, 512), Z, Z,
          in_b, nullptr, nullptr, nullptr, nullptr, nullptr, qkvc, nullptr,
          8192, 1536, 1536, 0, 0, 0, 0, 1.f, 0, 1);
    // scores[z=16] = 1/16 * Q @ K^T  -> bf16
    bgemm(stream, mkseg(qkvc, qkvc + 512, 256, 1536, 1536,
                        1572864, 1572864, 256, 256), Z, Z,
          nullptr, nullptr, nullptr, nullptr, nullptr, nullptr, sco, nullptr,
          1024, 1024, 1024, 2097152, 1048576, 1, 0, 0.0625f, 0, 16);
    softmaxu_k<<<16384, 256, 0, stream>>>(sco);
    transp_k<<<dim3(16, 4, 16), 256, 0, stream>>>(
        qkvc + 1024, vT, 1536, 1024, 1572864, 262144, 256, 1);
    // ctx = P @ V  (B = V^T rows = d, cols = s)
    bgemm(stream, mkseg(sco, vT, 1024, 1024, 1024,
                        2097152, 524288, 1048576, 262144), Z, Z,
          nullptr, nullptr, nullptr, nullptr, nullptr, nullptr,
          bf2 + row0 * 512, nullptr,
          1024, 256, 512, 524288, 256, 1, 0, 1.f, 0, 16);
  }

  // 4. attn_out -> bf16
  u16* aoc = (u16*)scr;                           // 32MB
  bgemm(stream, mkseg(bf2, outw, 512, 512, 512), Z, Z,
        out_b, nullptr, nullptr, nullptr, nullptr, nullptr, aoc, nullptr,
        Mtok, 512, 512, 0, 0, 0, 0, 1.f, 0, 1);

  // 5. x1 = LN(h + attn_out) -> hi (in place) + lo
  ln1_k<<<Mtok, 256, 0, stream>>>(bf1, aoc, ln1_g, ln1_b, bf1, lob);

  // 6+7. FFN
  u16* mid = (u16*)scr;                           // 64MB
  bgemm(stream, mkseg(bf1, fw1b, 512, 512, 512), Z, Z,
        fb1, nullptr, nullptr, nullptr, nullptr, nullptr, mid, nullptr,
        Mtok, 1024, 1024, 0, 0, 0, 0, 1.f, F_RELU, 1);
  bgemm(stream, mkseg(mid, fw2b, 1024, 1024, 1024), Z, Z,
        fb2, bf1, lob, nullptr, nullptr, nullptr, bf1, lob,
        Mtok, 512, 512, 0, 0, 0, 0, 1.f, F_RESID2, 1);

  // 8. row norms
  rownorm_k<<<Mtok, 256, 0, stream>>>(bf1, lob, invn);

  // 9-12. graph: x1T once, then 2 chunks x 16 batches; sim bf16 in-place adj
  u16* simadj = (u16*)scr;                        // 32MB (16 x 1024x1024 u16)
  u16* x1T    = (u16*)(scr + 33554432);           // 32MB (all 32 batches)
  transp_k<<<dim3(16, 8, 32), 256, 0, stream>>>(bf1, x1T, 512, 1024,
                                                524288, 524288, 0, 0);
  for (int g = 0; g < 2; ++g) {
    long row0 = (long)g * 16384;
    // sim = (hi.hi^T) * invn_i * invn_j  -> bf16
    bgemm(stream,
          mkseg(bf1 + row0 * 512, bf1 + row0 * 512, 512, 512, 512, 524288, 524288),
          Z, Z, nullptr, nullptr, nullptr, invn + row0, invn + row0,
          nullptr, simadj, nullptr,
          1024, 1024, 1024, 1048576, 0, 0, 1024, 1.f, F_SIMSC, 16);
    topk_k<<<16384, 256, 0, stream>>>(simadj, idx4 + row0 * 4);
    adjbf_k<<<16384, 256, 0, stream>>>(simadj, idx4 + row0 * 4, invcnt + row0);
    // nsum = (adj @ x1) * invcnt
    bgemm(stream, mkseg(simadj, x1T + row0 * 512, 1024, 1024, 1024,
                        1048576, 524288), Z, Z,
          nullptr, nullptr, nullptr, invcnt + row0, nullptr, nullptr,
          bf2 + row0 * 512, nullptr,
          1024, 512, 512, 524288, 0, 0, 1024, 1.f, F_ROWSC, 16);
  }

  // 13/14. gcout = x1_hi @ gcW1^T + nsum @ gcW2^T + gc_b  (2-seg) -> bf16
  u16* gch = (u16*)scr;                           // 32MB
  bgemm(stream, mkseg(bf1, gcwb, 512, 512, 1024),
        mkseg(bf2, gcwb + 512, 512, 512, 1024), Z,
        gc_b, nullptr, nullptr, nullptr, nullptr, nullptr, gch, nullptr,
        Mtok, 512, 512, 0, 0, 0, 0, 1.f, 0, 1);

  // 15. x2 = LN(x1 + gcout) -> bf16 (over bf2; nsum consumed)
  ln2_k<<<Mtok, 256, 0, stream>>>(bf1, lob, gch, ln2_g, ln2_b, bf2);

  // 16+17. pool + decoder
  poolbf_k<<<256, 256, 0, stream>>>(bf2, pooledb);
  bgemm(stream, mkseg(pooledb, decw, 512, 512, 512), Z, Z,
        dec_b, nullptr, nullptr, nullptr, nullptr, out, nullptr, nullptr,
        128, 512, 512, 0, 0, 0, 0, 1.f, 0, 1, 32);
}

// Round 9
// 1497.241 us; speedup vs baseline: 1.0857x; 1.0245x over previous
//
#include <hip/hip_runtime.h>
#include <hip/hip_bf16.h>
#include <math.h>

typedef unsigned short u16;
typedef __attribute__((ext_vector_type(8))) short bfrag;     // 8 bf16 (4 VGPR)
typedef __attribute__((ext_vector_type(16))) float facc16;   // 16 fp32 acc
typedef const __attribute__((address_space(1))) void* gaddr_t;
typedef __attribute__((address_space(3))) void* laddr_t;

#define F_RELU   1
#define F_ROWSC  4   // *= rsc[m]
#define F_SIMSC  8   // *= rsc[m]*csc[n]
#define F_RESID2 32  // += bf16 residH + residL
#define F_BIASM  64  // bias indexed by gm (row) instead of gn

__device__ __forceinline__ u16 f2bf(float f) {
  __hip_bfloat16 h = __float2bfloat16(f);
  return *reinterpret_cast<u16*>(&h);
}
__device__ __forceinline__ float bf2f(u16 u) {
  __hip_bfloat16 h = *reinterpret_cast<__hip_bfloat16*>(&u);
  return __bfloat162float(h);
}
__device__ __forceinline__ float wsum(float v) {
#pragma unroll
  for (int o = 32; o; o >>= 1) v += __shfl_xor(v, o);
  return v;
}
__device__ __forceinline__ float wmaxf(float v) {
#pragma unroll
  for (int o = 32; o; o >>= 1) v = fmaxf(v, __shfl_xor(v, o));
  return v;
}

struct GSeg {
  const u16* A; const u16* B;
  long sA, sB;          // per-z strides
  int lda, ldb, K;      // K % 64 == 0
  int hA, hB;           // per-head offsets (headBits mode)
};

// ---------------------------------------------------------------------------
// bf16 MFMA GEMM, up to 3 K-segments: C = epi(alpha * sum_s A_s @ B_s^T)
// 256 thr = 4 waves; tile 128x128; BK=64; dbuf LDS 2x32KB (R6 loop structure
// — best measured; R7's BK=32 dbuf regressed).
// R9: MFMA shape 32x32x16 (2x2 tiles/wave, 16 insts/iter vs 32) — µbench
// rate +15% over 16x16x32 and half the issue slots.
// A/B frag: row=lane&31, k=(lane>>5)*8+j. C/D: col=lane&31,
// row=(reg&3)+8*(reg>>2)+4*(lane>>5)  [m74/m101-verified].
// ---------------------------------------------------------------------------
__global__ __launch_bounds__(256)
void bgemm_k(GSeg s0, GSeg s1, GSeg s2,
             const float* __restrict__ bias,
             const u16* __restrict__ residH, const u16* __restrict__ residL,
             const float* __restrict__ rsc, const float* __restrict__ csc,
             float* __restrict__ Cf, u16* __restrict__ Cb, u16* __restrict__ Cb2,
             int ldc, long sC, int hC, int headBits, int sS,
             float alpha, int flags, int Mstore)
{
  const int zAll = blockIdx.z;
  const int hIdx = headBits ? (zAll & 1) : 0;
  const int z    = headBits ? (zAll >> 1) : zAll;
  const long cofs = (long)z * sC + (long)hIdx * hC;
  const float* rs = rsc ? rsc + (long)z * sS : nullptr;
  const float* cs = csc ? csc + (long)z * sS : nullptr;

  __shared__ u16 As[2][128 * 64];
  __shared__ u16 Bs[2][128 * 64];

  const int tid  = threadIdx.x;
  const int wave = tid >> 6, lane = tid & 63;
  const int m0 = blockIdx.x * 128, n0 = blockIdx.y * 128;
  const int wrow = (wave >> 1) * 64, wcol = (wave & 1) * 64;

  const u16* ApS[3]; const u16* BpS[3]; int ldaS[3], ldbS[3];
  ApS[0] = s0.A + (long)z * s0.sA + (long)hIdx * s0.hA;
  BpS[0] = s0.B + (long)z * s0.sB + (long)hIdx * s0.hB;
  ldaS[0] = s0.lda; ldbS[0] = s0.ldb;
  ApS[1] = s1.A ? s1.A + (long)z * s1.sA + (long)hIdx * s1.hA : nullptr;
  BpS[1] = s1.B ? s1.B + (long)z * s1.sB + (long)hIdx * s1.hB : nullptr;
  ldaS[1] = s1.lda; ldbS[1] = s1.ldb;
  ApS[2] = s2.A ? s2.A + (long)z * s2.sA + (long)hIdx * s2.hA : nullptr;
  BpS[2] = s2.B ? s2.B + (long)z * s2.sB + (long)hIdx * s2.hB : nullptr;
  ldaS[2] = s2.lda; ldbS[2] = s2.ldb;
  const int n0i = s0.K >> 6, n1i = n0i + (s1.K >> 6);
  const int nIt = n1i + (s2.K >> 6);

  const int lrow = lane >> 3;          // 0..7
  const int lgrp = lane & 7;           // 0..7

  facc16 acc[2][2];
#pragma unroll
  for (int i = 0; i < 2; ++i)
#pragma unroll
    for (int j = 0; j < 2; ++j) acc[i][j] = (facc16)(0.f);

  const int l31 = lane & 31, l5 = lane >> 5;

  auto stage = [&](int buf, int it) {
    int sidx, base;
    if (it < n0i)      { sidx = 0; base = 0; }
    else if (it < n1i) { sidx = 1; base = n0i; }
    else               { sidx = 2; base = n1i; }
    const int k0 = (it - base) << 6;
    const u16* Ab = ApS[sidx];
    const u16* Bb = BpS[sidx];
    const int la = ldaS[sidx], lb = ldbS[sidx];
#pragma unroll
    for (int ss = 0; ss < 4; ++ss) {
      int rloc = wave * 32 + ss * 8;
      int row  = rloc + lrow;
      int g    = lgrp ^ ((row >> 1) & 7);
      __builtin_amdgcn_global_load_lds(
          (gaddr_t)(const void*)(Ab + (long)(m0 + row) * la + k0 + g * 8),
          (laddr_t)(As[buf] + rloc * 64), 16, 0, 0);
      __builtin_amdgcn_global_load_lds(
          (gaddr_t)(const void*)(Bb + (long)(n0 + row) * lb + k0 + g * 8),
          (laddr_t)(Bs[buf] + rloc * 64), 16, 0, 0);
    }
  };

  stage(0, 0);
  for (int it = 0; it < nIt; ++it) {
    const int buf = it & 1;
    __syncthreads();                      // drains glds; buf ready
    if (it + 1 < nIt) stage(buf ^ 1, it + 1);

#pragma unroll
    for (int ks = 0; ks < 4; ++ks) {      // K=16 per MFMA step
      const int gg = ks * 2 + l5;
      bfrag af[2], bb[2];
#pragma unroll
      for (int mt = 0; mt < 2; ++mt) {
        int r = wrow + mt * 32 + l31;
        int slot = gg ^ ((r >> 1) & 7);
        af[mt] = *(const bfrag*)&As[buf][r * 64 + slot * 8];
      }
#pragma unroll
      for (int nt = 0; nt < 2; ++nt) {
        int r = wcol + nt * 32 + l31;
        int slot = gg ^ ((r >> 1) & 7);
        bb[nt] = *(const bfrag*)&Bs[buf][r * 64 + slot * 8];
      }
#pragma unroll
      for (int mt = 0; mt < 2; ++mt)
#pragma unroll
        for (int nt = 0; nt < 2; ++nt)
          acc[mt][nt] = __builtin_amdgcn_mfma_f32_32x32x16_bf16(
              af[mt], bb[nt], acc[mt][nt], 0, 0, 0);
    }
  }

  // epilogue: C/D col = lane&31, row = (reg&3) + 8*(reg>>2) + 4*(lane>>5)
#pragma unroll
  for (int mt = 0; mt < 2; ++mt) {
#pragma unroll
    for (int nt = 0; nt < 2; ++nt) {
#pragma unroll
      for (int rg = 0; rg < 16; ++rg) {
        int gm = m0 + wrow + mt * 32 + (rg & 3) + 8 * (rg >> 2) + 4 * l5;
        int gn = n0 + wcol + nt * 32 + l31;
        if (gm >= Mstore) continue;
        float v = acc[mt][nt][rg] * alpha;
        long ci = cofs + (long)gm * ldc + gn;
        if (flags & F_SIMSC)  v *= rs[gm] * cs[gn];
        if (flags & F_ROWSC)  v *= rs[gm];
        if (bias)             v += bias[(flags & F_BIASM) ? gm : gn];
        if (flags & F_RESID2) v += bf2f(residH[ci]) + bf2f(residL[ci]);
        if (flags & F_RELU)   v = fmaxf(v, 0.f);
        if (Cf) Cf[ci] = v;
        if (Cb) {
          u16 hv = f2bf(v);
          Cb[ci] = hv;
          if (Cb2) Cb2[ci] = f2bf(v - bf2f(hv));
        }
      }
    }
  }
}

// ---------------------------------------------------------------------------
__global__ __launch_bounds__(256)
void castbf_k(const float* __restrict__ in, u16* __restrict__ out, int n)
{
  int i = blockIdx.x * 256 + threadIdx.x;
  if (i < n) out[i] = f2bf(in[i]);
}

// all 7 weight matrices in one launch (layout matches wgt arena)
__global__ __launch_bounds__(256)
void castw_k(const float* w0, const float* w1, const float* w2,
             const float* w3, const float* w4, const float* w5,
             const float* w6, u16* __restrict__ dst)
{
  int i = blockIdx.x * 256 + threadIdx.x;
  const float* s; int off;
  if      (i < 262144)  { s = w0; off = 0; }
  else if (i < 1048576) { s = w1; off = 262144; }
  else if (i < 1310720) { s = w2; off = 1048576; }
  else if (i < 1835008) { s = w3; off = 1310720; }
  else if (i < 2359296) { s = w4; off = 1835008; }
  else if (i < 2883584) { s = w5; off = 2359296; }
  else                  { s = w6; off = 2883584; }
  dst[i] = f2bf(s[i - off]);
}

// x1 = LN(bf16 a + bf16 b) -> hi (in place over a ok) + lo
__global__ __launch_bounds__(256)
void ln1_k(const u16* __restrict__ a, const u16* __restrict__ b,
           const float* __restrict__ g, const float* __restrict__ be,
           u16* __restrict__ oh, u16* __restrict__ ol)
{
  long base = (long)blockIdx.x * 512;
  int t = threadIdx.x;
  float v0 = bf2f(a[base + t])       + bf2f(b[base + t]);
  float v1 = bf2f(a[base + t + 256]) + bf2f(b[base + t + 256]);
  __shared__ float red[4], red2[4];
  float s = wsum(v0 + v1);
  if ((t & 63) == 0) red[t >> 6] = s;
  __syncthreads();
  float mean = (red[0] + red[1] + red[2] + red[3]) * (1.f / 512.f);
  float c0 = v0 - mean, c1 = v1 - mean;
  float ss = wsum(c0 * c0 + c1 * c1);
  if ((t & 63) == 0) red2[t >> 6] = ss;
  __syncthreads();
  float var = (red2[0] + red2[1] + red2[2] + red2[3]) * (1.f / 512.f);
  float rstd = rsqrtf(var + 1e-5f);
  float o0 = c0 * rstd * g[t]       + be[t];
  float o1 = c1 * rstd * g[t + 256] + be[t + 256];
  u16 h0 = f2bf(o0), h1 = f2bf(o1);
  oh[base + t] = h0;       oh[base + t + 256] = h1;
  ol[base + t] = f2bf(o0 - bf2f(h0));
  ol[base + t + 256] = f2bf(o1 - bf2f(h1));
}

// x2 = LN((hi+lo) + bf16 b) -> bf16
__global__ __launch_bounds__(256)
void ln2_k(const u16* __restrict__ hi, const u16* __restrict__ lo,
           const u16* __restrict__ b, const float* __restrict__ g,
           const float* __restrict__ be, u16* __restrict__ ob)
{
  long base = (long)blockIdx.x * 512;
  int t = threadIdx.x;
  float v0 = bf2f(hi[base + t])       + bf2f(lo[base + t])       + bf2f(b[base + t]);
  float v1 = bf2f(hi[base + t + 256]) + bf2f(lo[base + t + 256]) + bf2f(b[base + t + 256]);
  __shared__ float red[4], red2[4];
  float s = wsum(v0 + v1);
  if ((t & 63) == 0) red[t >> 6] = s;
  __syncthreads();
  float mean = (red[0] + red[1] + red[2] + red[3]) * (1.f / 512.f);
  float c0 = v0 - mean, c1 = v1 - mean;
  float ss = wsum(c0 * c0 + c1 * c1);
  if ((t & 63) == 0) red2[t >> 6] = ss;
  __syncthreads();
  float var = (red2[0] + red2[1] + red2[2] + red2[3]) * (1.f / 512.f);
  float rstd = rsqrtf(var + 1e-5f);
  ob[base + t]       = f2bf(c0 * rstd * g[t]       + be[t]);
  ob[base + t + 256] = f2bf(c1 * rstd * g[t + 256] + be[t + 256]);
}

// invn[row] = 1/max(||hi+lo||, 1e-12)
__global__ __launch_bounds__(256)
void rownorm_k(const u16* __restrict__ hi, const u16* __restrict__ lo,
               float* __restrict__ invn)
{
  long base = (long)blockIdx.x * 512;
  int t = threadIdx.x;
  float v0 = bf2f(hi[base + t])       + bf2f(lo[base + t]);
  float v1 = bf2f(hi[base + t + 256]) + bf2f(lo[base + t + 256]);
  __shared__ float red[4];
  float s = wsum(v0 * v0 + v1 * v1);
  if ((t & 63) == 0) red[t >> 6] = s;
  __syncthreads();
  if (t == 0) {
    float tot = red[0] + red[1] + red[2] + red[3];
    invn[blockIdx.x] = 1.f / fmaxf(sqrtf(tot), 1e-12f);
  }
}

// in-place row softmax over 1024 bf16
__global__ __launch_bounds__(256)
void softmaxu_k(u16* __restrict__ sc)
{
  long row = blockIdx.x;
  u16* p = sc + row * 1024;
  int t = threadIdx.x;
  float v[4];
#pragma unroll
  for (int i = 0; i < 4; ++i) v[i] = bf2f(p[t + 256 * i]);
  __shared__ float redm[4], redsum[4];
  float m4 = fmaxf(fmaxf(v[0], v[1]), fmaxf(v[2], v[3]));
  float wm = wmaxf(m4);
  if ((t & 63) == 0) redm[t >> 6] = wm;
  __syncthreads();
  float MX = fmaxf(fmaxf(redm[0], redm[1]), fmaxf(redm[2], redm[3]));
  float s = 0.f;
#pragma unroll
  for (int i = 0; i < 4; ++i) { v[i] = __expf(v[i] - MX); s += v[i]; }
  float ws_ = wsum(s);
  if ((t & 63) == 0) redsum[t >> 6] = ws_;
  __syncthreads();
  float inv = 1.f / (redsum[0] + redsum[1] + redsum[2] + redsum[3]);
#pragma unroll
  for (int i = 0; i < 4; ++i) p[t + 256 * i] = f2bf(v[i] * inv);
}

// 64x64 tiled u16 transpose (used only for x1T now)
__global__ __launch_bounds__(256)
void transp_k(const u16* __restrict__ in, u16* __restrict__ out,
              int inStride, int outStride, long sIn, long sOut)
{
  const int z = blockIdx.z;
  const u16* src = in + (long)z * sIn;
  u16* dst = out + (long)z * sOut;
  const int r0 = blockIdx.x * 64, c0 = blockIdx.y * 64;
  __shared__ u16 tile[64][66];
  const int t = threadIdx.x;
#pragma unroll
  for (int p = 0; p < 16; ++p) {
    int idx = p * 256 + t;
    int r = idx >> 6, c = idx & 63;
    tile[r][c] = src[(long)(r0 + r) * inStride + c0 + c];
  }
  __syncthreads();
#pragma unroll
  for (int p = 0; p < 16; ++p) {
    int idx = p * 256 + t;
    int c = idx >> 6, r = idx & 63;
    dst[(long)(c0 + c) * outStride + r0 + r] = tile[r][c];
  }
}

// per-row top-4 from bf16 sim, row cached in LDS (one HBM read per row).
__global__ __launch_bounds__(256)
void topk_k(const u16* __restrict__ sim, int* __restrict__ idx4)
{
  __shared__ float row[1024];
  __shared__ float bv[4];
  __shared__ int   bidx[4];
  long r = blockIdx.x;
  const u16* p = sim + r * 1024;
  int t = threadIdx.x;
  for (int i = t; i < 1024; i += 256) row[i] = bf2f(p[i]);
  __syncthreads();
  int c0 = -1, c1 = -1, c2 = -1, c3 = -1;
#pragma unroll
  for (int pass = 0; pass < 4; ++pass) {
    float best = -INFINITY;
    int bi = 1 << 30;
#pragma unroll
    for (int q = 0; q < 4; ++q) {
      int j = t + q * 256;
      if (j == c0 || j == c1 || j == c2 || j == c3) continue;
      float v = row[j];
      if (v > best || (v == best && j < bi)) { best = v; bi = j; }
    }
#pragma unroll
    for (int off = 32; off; off >>= 1) {
      float ov = __shfl_down(best, off);
      int   oi = __shfl_down(bi, off);
      if (ov > best || (ov == best && oi < bi)) { best = ov; bi = oi; }
    }
    if ((t & 63) == 0) { bv[t >> 6] = best; bidx[t >> 6] = bi; }
    __syncthreads();
    if (t == 0) {
      float bb = bv[0]; int ii = bidx[0];
#pragma unroll
      for (int w = 1; w < 4; ++w)
        if (bv[w] > bb || (bv[w] == bb && bidx[w] < ii)) { bb = bv[w]; ii = bidx[w]; }
      bidx[0] = ii;
    }
    __syncthreads();
    int sel = bidx[0];
    if (pass == 0) c0 = sel; else if (pass == 1) c1 = sel;
    else if (pass == 2) c2 = sel; else c3 = sel;
    __syncthreads();
  }
  if (t == 0) { int* q = idx4 + r * 4; q[0] = c0; q[1] = c1; q[2] = c2; q[3] = c3; }
}

// adjacency IN PLACE over bf16 sim + invcnt (chunk-local rows)
__global__ __launch_bounds__(256)
void adjbf_k(u16* __restrict__ simadj, const int* __restrict__ idx4,
             float* __restrict__ invcnt)
{
  long row = blockIdx.x;
  int b = (int)(row >> 10);
  int i = (int)(row & 1023);
  u16* prow = simadj + row * 1024;
  const int* my = idx4 + row * 4;
  int m0 = my[0], m1 = my[1], m2 = my[2], m3 = my[3];
  int t = threadIdx.x;
  float lsum = 0.f;
  for (int j = t; j < 1024; j += 256) {
    float v = bf2f(prow[j]);
    bool present = false;
    if (j != i) {
      present = (j == m0) | (j == m1) | (j == m2) | (j == m3);
      if (!present) {
        const int* oj = idx4 + (((long)b << 10) + j) * 4;
        present = (oj[0] == i) | (oj[1] == i) | (oj[2] == i) | (oj[3] == i);
      }
    }
    float a = present ? v : 0.f;
    prow[j] = present ? prow[j] : (u16)0;
    lsum += a;
  }
  __shared__ float red[4];
  float s = wsum(lsum);
  if ((t & 63) == 0) red[t >> 6] = s;
  __syncthreads();
  if (t == 0) {
    float tot = red[0] + red[1] + red[2] + red[3];
    invcnt[row] = 1.f / fmaxf(tot, 1.f);
  }
}

// pooled_bf[128][512]: rows<32 = mean_s x2_bf, rows>=32 = 0
__global__ __launch_bounds__(256)
void poolbf_k(const u16* __restrict__ x2, u16* __restrict__ pooled)
{
  int i = blockIdx.x * 256 + threadIdx.x;   // 0..65535
  int b = i >> 9, d = i & 511;
  float s = 0.f;
  if (b < 32) {
    const u16* p = x2 + ((long)b << 10) * 512 + d;
    for (int sdx = 0; sdx < 1024; ++sdx) s += bf2f(p[(long)sdx * 512]);
    s *= (1.f / 1024.f);
  }
  pooled[i] = f2bf(s);
}

// ---------------------------------------------------------------------------
static inline GSeg mkseg(const u16* A, const u16* B, int K, int lda, int ldb,
                         long sA = 0, long sB = 0, int hA = 0, int hB = 0)
{
  GSeg s; s.A = A; s.B = B; s.K = K; s.lda = lda; s.ldb = ldb;
  s.sA = sA; s.sB = sB; s.hA = hA; s.hB = hB; return s;
}

static inline void bgemm(hipStream_t st, GSeg s0, GSeg s1, GSeg s2,
    const float* bias, const u16* residH, const u16* residL,
    const float* rsc, const float* csc, float* Cf, u16* Cb, u16* Cb2,
    int M, int N, int ldc, long sC, int hC, int headBits, int sS,
    float alpha, int flags, int nz, int Mstore = -1)
{
  dim3 g(M / 128, N / 128, nz);
  bgemm_k<<<g, 256, 0, st>>>(s0, s1, s2, bias, residH, residL,
                             rsc, csc, Cf, Cb, Cb2, ldc, sC, hC, headBits,
                             sS, alpha, flags, Mstore < 0 ? M : Mstore);
}

extern "C" void kernel_launch(void* const* d_in, const int* in_sizes, int n_in,
                              void* d_out, int out_size, void* d_ws, size_t ws_size,
                              hipStream_t stream)
{
  (void)in_sizes; (void)n_in; (void)out_size;
  const float* x     = (const float*)d_in[0];
  const float* enc_w = (const float*)d_in[1];
  const float* enc_b = (const float*)d_in[2];
  const float* in_w  = (const float*)d_in[3];
  const float* in_b  = (const float*)d_in[4];
  const float* out_w = (const float*)d_in[5];
  const float* out_b = (const float*)d_in[6];
  const float* ln1_g = (const float*)d_in[7];
  const float* ln1_b = (const float*)d_in[8];
  const float* fw1   = (const float*)d_in[9];
  const float* fb1   = (const float*)d_in[10];
  const float* fw2   = (const float*)d_in[11];
  const float* fb2   = (const float*)d_in[12];
  const float* gc_w  = (const float*)d_in[13];
  const float* gc_b  = (const float*)d_in[14];
  const float* ln2_g = (const float*)d_in[15];
  const float* ln2_b = (const float*)d_in[16];
  const float* dec_w = (const float*)d_in[17];
  const float* dec_b = (const float*)d_in[18];
  float* out = (float*)d_out;

  // ---- arena ----
  char* base = (char*)d_ws;
  u16*  bf1  = (u16*)(base);                  // h_bf -> x1_hi (in place)
  u16*  lob  = (u16*)(base + 33554432);       // vT (attention) -> x1_lo
  u16*  bf2  = (u16*)(base + 67108864);       // ctx -> nsum -> x2
  u16*  wgt  = (u16*)(base + 100663296);      // bf16 weights
  float* invn    = (float*)(base + 106954752);
  float* invcnt  = (float*)(base + 107085824);
  u16*   pooledb = (u16*)(base + 107216896);
  int*   idx4    = (int*)(base + 107347968);
  char*  scr     = base + 107872256;          // 80MB scratch, phase-multiplexed
  const size_t need = 107872256 + 83886080;
  if (ws_size < need) return;

  u16* encw = wgt;
  u16* inw  = wgt + 262144;
  u16* outw = wgt + 1048576;
  u16* fw1b = wgt + 1310720;
  u16* fw2b = wgt + 1835008;
  u16* gcwb = wgt + 2359296;
  u16* decw = wgt + 2883584;

  const int Mtok = 32768;
  GSeg Z = mkseg(nullptr, nullptr, 0, 0, 0);

  // ---- casts ----
  u16* xbf = (u16*)scr;
  castbf_k<<<65536, 256, 0, stream>>>(x, xbf, 16777216);
  castw_k<<<12288, 256, 0, stream>>>(enc_w, in_w, out_w, fw1, fw2, gc_w, dec_w, wgt);

  // 1. h_bf = relu(x @ enc_w^T + enc_b)
  bgemm(stream, mkseg(xbf, encw, 512, 512, 512), Z, Z,
        enc_b, nullptr, nullptr, nullptr, nullptr, nullptr, bf1, nullptr,
        Mtok, 512, 512, 0, 0, 0, 0, 1.f, F_RELU, 1);

  // 2. vT = Wv @ h^T  (A/B-swapped GEMM, per-row bias) -> lob [512][32768]
  bgemm(stream, mkseg(inw + 524288, bf1, 512, 512, 512), Z, Z,
        in_b + 1024, nullptr, nullptr, nullptr, nullptr, nullptr,
        lob, nullptr, 512, Mtok, Mtok, 0, 0, 0, 0, 1.f, F_BIASM, 1);

  // 3. attention: 4 chunks x 8 batches, heads folded into z (z=16)
  for (int c = 0; c < 4; ++c) {
    long row0 = (long)c * 8192;
    u16* qkc = (u16*)scr;                         // 8192x1024 u16 (16MB)
    u16* sco = (u16*)(scr + 16777216);            // 16 x 1024x1024 u16 (32MB)
    bgemm(stream, mkseg(bf1 + row0 * 512, inw, 512, 512, 512), Z, Z,
          in_b, nullptr, nullptr, nullptr, nullptr, nullptr, qkc, nullptr,
          8192, 1024, 1024, 0, 0, 0, 0, 1.f, 0, 1);
    // scores[z=16] = 1/16 * Q @ K^T  -> bf16
    bgemm(stream, mkseg(qkc, qkc + 512, 256, 1024, 1024,
                        1048576, 1048576, 256, 256), Z, Z,
          nullptr, nullptr, nullptr, nullptr, nullptr, nullptr, sco, nullptr,
          1024, 1024, 1024, 2097152, 1048576, 1, 0, 0.0625f, 0, 16);
    softmaxu_k<<<16384, 256, 0, stream>>>(sco);
    // ctx = P @ V   (B = vT rows d, per-batch col offset, per-head row offset)
    bgemm(stream, mkseg(sco, lob + (row0 >> 10) * 1024, 1024, 1024, Mtok,
                        2097152, 1024, 1048576, 8388608), Z, Z,
          nullptr, nullptr, nullptr, nullptr, nullptr, nullptr,
          bf2 + row0 * 512, nullptr,
          1024, 256, 512, 524288, 256, 1, 0, 1.f, 0, 16);
  }

  // 4. attn_out -> bf16
  u16* aoc = (u16*)scr;                           // 32MB
  bgemm(stream, mkseg(bf2, outw, 512, 512, 512), Z, Z,
        out_b, nullptr, nullptr, nullptr, nullptr, nullptr, aoc, nullptr,
        Mtok, 512, 512, 0, 0, 0, 0, 1.f, 0, 1);

  // 5. x1 = LN(h + attn_out) -> hi (in place) + lo (lob; vT consumed)
  ln1_k<<<Mtok, 256, 0, stream>>>(bf1, aoc, ln1_g, ln1_b, bf1, lob);

  // 6+7. FFN
  u16* mid = (u16*)scr;                           // 64MB
  bgemm(stream, mkseg(bf1, fw1b, 512, 512, 512), Z, Z,
        fb1, nullptr, nullptr, nullptr, nullptr, nullptr, mid, nullptr,
        Mtok, 1024, 1024, 0, 0, 0, 0, 1.f, F_RELU, 1);
  bgemm(stream, mkseg(mid, fw2b, 1024, 1024, 1024), Z, Z,
        fb2, bf1, lob, nullptr, nullptr, nullptr, bf1, lob,
        Mtok, 512, 512, 0, 0, 0, 0, 1.f, F_RESID2, 1);

  // 8. row norms
  rownorm_k<<<Mtok, 256, 0, stream>>>(bf1, lob, invn);

  // 9-12. graph: x1T once, then 2 chunks x 16 batches; sim bf16 in-place adj
  u16* simadj = (u16*)scr;                        // 32MB (16 x 1024x1024 u16)
  u16* x1T    = (u16*)(scr + 33554432);           // 32MB (all 32 batches)
  transp_k<<<dim3(16, 8, 32), 256, 0, stream>>>(bf1, x1T, 512, 1024,
                                                524288, 524288);
  for (int g = 0; g < 2; ++g) {
    long row0 = (long)g * 16384;
    // sim = (hi.hi^T) * invn_i * invn_j  -> bf16
    bgemm(stream,
          mkseg(bf1 + row0 * 512, bf1 + row0 * 512, 512, 512, 512, 524288, 524288),
          Z, Z, nullptr, nullptr, nullptr, invn + row0, invn + row0,
          nullptr, simadj, nullptr,
          1024, 1024, 1024, 1048576, 0, 0, 1024, 1.f, F_SIMSC, 16);
    topk_k<<<16384, 256, 0, stream>>>(simadj, idx4 + row0 * 4);
    adjbf_k<<<16384, 256, 0, stream>>>(simadj, idx4 + row0 * 4, invcnt + row0);
    // nsum = (adj @ x1) * invcnt
    bgemm(stream, mkseg(simadj, x1T + row0 * 512, 1024, 1024, 1024,
                        1048576, 524288), Z, Z,
          nullptr, nullptr, nullptr, invcnt + row0, nullptr, nullptr,
          bf2 + row0 * 512, nullptr,
          1024, 512, 512, 524288, 0, 0, 1024, 1.f, F_ROWSC, 16);
  }

  // 13/14. gcout = x1_hi @ gcW1^T + nsum @ gcW2^T + gc_b  (2-seg) -> bf16
  u16* gch = (u16*)scr;                           // 32MB
  bgemm(stream, mkseg(bf1, gcwb, 512, 512, 1024),
        mkseg(bf2, gcwb + 512, 512, 512, 1024), Z,
        gc_b, nullptr, nullptr, nullptr, nullptr, nullptr, gch, nullptr,
        Mtok, 512, 512, 0, 0, 0, 0, 1.f, 0, 1);

  // 15. x2 = LN(x1 + gcout) -> bf16 (over bf2; nsum consumed)
  ln2_k<<<Mtok, 256, 0, stream>>>(bf1, lob, gch, ln2_g, ln2_b, bf2);

  // 16+17. pool + decoder
  poolbf_k<<<256, 256, 0, stream>>>(bf2, pooledb);
  bgemm(stream, mkseg(pooledb, decw, 512, 512, 512), Z, Z,
        dec_b, nullptr, nullptr, nullptr, nullptr, out, nullptr, nullptr,
        128, 512, 512, 0, 0, 0, 0, 1.f, 0, 1, 32);
}